// Round 14
// baseline (231.054 us; speedup 1.0000x reference)
//
#include <hip/hip_runtime.h>
#include <math.h>

#define BATCH   4
#define SEQLEN  4096
#define NDIM    256
#define DINNER  512
#define DSTATE  16
#define M_ROWS  (BATCH*SEQLEN)   // 16384
#define CHUNK   32
#define NCHUNK  (SEQLEN/CHUNK)   // 128

typedef _Float16 half8 __attribute__((ext_vector_type(8)));
typedef _Float16 half4 __attribute__((ext_vector_type(4)));
typedef float floatx4 __attribute__((ext_vector_type(4)));

// ---------------------------------------------------------------------------
// prep_all: weight conversion/packing only (x consumed fp32 by K1 directly).
// blocks [0,1024): x_proj -> W1h B-frag order
// blocks [1024,1536): out_proj -> W4h B-frag order
// blocks [1536,1664): [Wdt|Wb|Wc|0] -> Wphi/Wplo B-frag order (hi/lo)
// ---------------------------------------------------------------------------
__global__ __launch_bounds__(256)
void prep_all(const float* __restrict__ Wx, const float* __restrict__ Wo,
              const float* __restrict__ Wdt, const float* __restrict__ Wb,
              const float* __restrict__ Wc,
              _Float16* __restrict__ W1h, _Float16* __restrict__ W4h,
              _Float16* __restrict__ Wphi, _Float16* __restrict__ Wplo) {
    const int bid = blockIdx.x;
    const int tid = threadIdx.x;
    if (bid < 1024) {
        const int t = bid * 256 + tid;               // x_proj: N=1024
        const int j  = t & 7;
        const int n  = (t >> 3) & 1023;
        const int q  = (t >> 13) & 3;
        const int kb = t >> 15;
        const int k  = kb * 32 + q * 8 + j;
        W1h[t] = (_Float16)Wx[(size_t)k * 1024 + n];
    } else if (bid < 1536) {
        const int t = (bid - 1024) * 256 + tid;      // out_proj: N=256
        const int j  = t & 7;
        const int n  = (t >> 3) & 255;
        const int q  = (t >> 11) & 3;
        const int kb = t >> 13;
        const int k  = kb * 32 + q * 8 + j;
        W4h[t] = (_Float16)Wo[(size_t)k * 256 + n];
    } else {
        const int t = (bid - 1536) * 256 + tid;      // proj weights, N=64
        const int n  = (t >> 3) & 63;
        const int q  = (t >> 9) & 3;
        const int kb = t >> 11;
        const int k  = kb * 32 + q * 8 + (t & 7);
        float v;
        if      (n < 16) v = Wdt[(size_t)k * 16 + n];
        else if (n < 32) v = Wb [(size_t)k * 16 + (n - 16)];
        else if (n < 48) v = Wc [(size_t)k * 16 + (n - 32)];
        else             v = 0.f;
        const _Float16 hi = (_Float16)v;
        Wphi[t] = hi;
        Wplo[t] = (_Float16)(v - (float)hi);
    }
}

// ---------------------------------------------------------------------------
// K1: fp16 MFMA GEMM reading fp32 x DIRECTLY (in-register convert; VALU is
// otherwise idle). NO LDS. 1-D grid 1024, XCD-swizzled (by=bid&127 -> one
// XCD owns all n-tiles of an m-block). silu -> fp16 U / G.
// ---------------------------------------------------------------------------
__global__ __launch_bounds__(256)
void mfma_gemm1(const float* __restrict__ X, const _Float16* __restrict__ Wh,
                _Float16* __restrict__ O1, _Float16* __restrict__ O2) {
    const int KT = 256, NT = 1024;
    const int bid = blockIdx.x;
    const int by = bid & 127;
    const int bx = bid >> 7;
    const int tid = threadIdx.x;
    const int lane = tid & 63;
    const int w  = tid >> 6;
    const int wm = w >> 1, wn = w & 1;
    const int n0 = bx * 128;
    const int m0 = by * 128;
    const int l15 = lane & 15, q = lane >> 4;

    floatx4 acc[4][4];
    const floatx4 zero = {0.f, 0.f, 0.f, 0.f};
    #pragma unroll
    for (int i = 0; i < 4; i++)
        #pragma unroll
        for (int j = 0; j < 4; j++) acc[i][j] = zero;

    const float* aBase = X + (size_t)(m0 + wm * 64 + l15) * KT + q * 8;

    for (int kb = 0; kb < KT / 32; kb++) {
        half8 b[4], a[4];
        #pragma unroll
        for (int mt = 0; mt < 4; mt++) {
            const float* ap = aBase + (size_t)(mt * 16) * KT + kb * 32;
            const float4 f0 = *(const float4*)ap;
            const float4 f1 = *(const float4*)(ap + 4);
            half8 av;
            av[0] = (_Float16)f0.x; av[1] = (_Float16)f0.y;
            av[2] = (_Float16)f0.z; av[3] = (_Float16)f0.w;
            av[4] = (_Float16)f1.x; av[5] = (_Float16)f1.y;
            av[6] = (_Float16)f1.z; av[7] = (_Float16)f1.w;
            a[mt] = av;
        }
        #pragma unroll
        for (int nt = 0; nt < 4; nt++) {
            const size_t off =
                ((size_t)((kb * 4 + q) * NT) + n0 + wn * 64 + nt * 16 + l15) * 8;
            b[nt] = *(const half8*)(Wh + off);
        }
        #pragma unroll
        for (int mt = 0; mt < 4; mt++)
            #pragma unroll
            for (int nt = 0; nt < 4; nt++)
                acc[mt][nt] = __builtin_amdgcn_mfma_f32_16x16x32_f16(
                    a[mt], b[nt], acc[mt][nt], 0, 0, 0);
    }
    // epilogue: D col=lane&15, row=quad*4+reg  [verified m89/m91; dtype-indep]
    #pragma unroll
    for (int mt = 0; mt < 4; mt++) {
        #pragma unroll
        for (int nt = 0; nt < 4; nt++) {
            const int col = n0 + wn * 64 + nt * 16 + l15;
            #pragma unroll
            for (int r = 0; r < 4; r++) {
                const int row = m0 + wm * 64 + mt * 16 + q * 4 + r;
                float v = acc[mt][nt][r];
                v = v / (1.f + __expf(-v));
                if (col < DINNER) O1[(size_t)row * DINNER + col] = (_Float16)v;
                else              O2[(size_t)row * DINNER + col - DINNER] = (_Float16)v;
            }
        }
    }
}

// ---------------------------------------------------------------------------
// K4: single-product fp16 MFMA GEMM, NO LDS, XCD-swizzled. Out fp32.
// ---------------------------------------------------------------------------
__global__ __launch_bounds__(256)
void mfma_gemm4(const _Float16* __restrict__ Ah, const _Float16* __restrict__ Wh,
                float* __restrict__ Out) {
    const int KT = 512, NT = 256;
    const int bid = blockIdx.x;
    const int by = bid & 127;
    const int bx = bid >> 7;
    const int tid = threadIdx.x;
    const int lane = tid & 63;
    const int w  = tid >> 6;
    const int wm = w >> 1, wn = w & 1;
    const int n0 = bx * 64;
    const int m0 = by * 128;
    const int l15 = lane & 15, q = lane >> 4;

    floatx4 acc[4][2];
    const floatx4 zero = {0.f, 0.f, 0.f, 0.f};
    #pragma unroll
    for (int i = 0; i < 4; i++)
        #pragma unroll
        for (int j = 0; j < 2; j++) acc[i][j] = zero;

    const _Float16* aBase = Ah + (size_t)(m0 + wm * 64 + l15) * KT + q * 8;

    for (int kb = 0; kb < KT / 32; kb++) {
        half8 b[2], a[4];
        #pragma unroll
        for (int mt = 0; mt < 4; mt++)
            a[mt] = *(const half8*)(aBase + (size_t)(mt * 16) * KT + kb * 32);
        #pragma unroll
        for (int nt = 0; nt < 2; nt++) {
            const size_t off =
                ((size_t)((kb * 4 + q) * NT) + n0 + wn * 32 + nt * 16 + l15) * 8;
            b[nt] = *(const half8*)(Wh + off);
        }
        #pragma unroll
        for (int mt = 0; mt < 4; mt++)
            #pragma unroll
            for (int nt = 0; nt < 2; nt++)
                acc[mt][nt] = __builtin_amdgcn_mfma_f32_16x16x32_f16(
                    a[mt], b[nt], acc[mt][nt], 0, 0, 0);
    }
    #pragma unroll
    for (int mt = 0; mt < 4; mt++) {
        #pragma unroll
        for (int nt = 0; nt < 2; nt++) {
            const int col = n0 + wn * 32 + nt * 16 + l15;
            #pragma unroll
            for (int r = 0; r < 4; r++) {
                const int row = m0 + wm * 64 + mt * 16 + q * 4 + r;
                Out[(size_t)row * NT + col] = acc[mt][nt][r];
            }
        }
    }
}

// ---------------------------------------------------------------------------
// proj_mfma (2-product, NO LDS): U fp16 @ Wp (512x64 hi/lo; 48 real cols) ->
// DT (softplus+bias) / BM / CM. 256 blocks x 64 rows.
// ---------------------------------------------------------------------------
__global__ __launch_bounds__(256)
void proj_mfma(const _Float16* __restrict__ Uh,
               const _Float16* __restrict__ Whi, const _Float16* __restrict__ Wlo,
               const float* __restrict__ bias,
               float* __restrict__ DT, float* __restrict__ BM,
               float* __restrict__ CM) {
    const int tid = threadIdx.x;
    const int lane = tid & 63;
    const int w  = tid >> 6;
    const int wm = w >> 1, wn = w & 1;
    const int m0 = blockIdx.x * 64;
    const int l15 = lane & 15, q = lane >> 4;

    floatx4 acc[2][2];
    const floatx4 zero = {0.f, 0.f, 0.f, 0.f};
    #pragma unroll
    for (int i = 0; i < 2; i++)
        #pragma unroll
        for (int j = 0; j < 2; j++) acc[i][j] = zero;

    const _Float16* aBase = Uh + (size_t)(m0 + wm * 32 + l15) * DINNER + q * 8;

    for (int kb = 0; kb < DINNER / 32; kb++) {
        half8 bh[2], bl[2], a[2];
        #pragma unroll
        for (int mt = 0; mt < 2; mt++)
            a[mt] = *(const half8*)(aBase + (size_t)(mt * 16) * DINNER + kb * 32);
        #pragma unroll
        for (int nt = 0; nt < 2; nt++) {
            const size_t off =
                ((size_t)((kb * 4 + q) * 64) + wn * 32 + nt * 16 + l15) * 8;
            bh[nt] = *(const half8*)(Whi + off);
            bl[nt] = *(const half8*)(Wlo + off);
        }
        #pragma unroll
        for (int mt = 0; mt < 2; mt++)
            #pragma unroll
            for (int nt = 0; nt < 2; nt++) {
                acc[mt][nt] = __builtin_amdgcn_mfma_f32_16x16x32_f16(
                    a[mt], bh[nt], acc[mt][nt], 0, 0, 0);
                acc[mt][nt] = __builtin_amdgcn_mfma_f32_16x16x32_f16(
                    a[mt], bl[nt], acc[mt][nt], 0, 0, 0);
            }
    }
    #pragma unroll
    for (int mt = 0; mt < 2; mt++) {
        #pragma unroll
        for (int nt = 0; nt < 2; nt++) {
            const int col = wn * 32 + nt * 16 + l15;
            #pragma unroll
            for (int r = 0; r < 4; r++) {
                const int row = m0 + wm * 32 + mt * 16 + q * 4 + r;
                float v = acc[mt][nt][r];
                if (col < 16) {
                    float dv = v + bias[col];
                    dv = (dv > 20.f) ? dv : log1pf(__expf(dv));
                    DT[(size_t)row * 16 + col] = dv;
                } else if (col < 32) {
                    BM[(size_t)row * 16 + (col - 16)] = v;
                } else if (col < 48) {
                    CM[(size_t)row * 16 + (col - 32)] = v;
                }
            }
        }
    }
}

// ---------------------------------------------------------------------------
// K3a: chunked scan phase A (CHUNK=32, 1024 blocks). One thread per d;
// states in floatx4[4]; LDS read as b128. [R12-proven 3-dispatch scan:
// cooperative grid.sync under graph capture is NOT trustworthy — R13 failed.]
// ---------------------------------------------------------------------------
__global__ __launch_bounds__(256)
void scan_phase_a(const float* __restrict__ DT, const float* __restrict__ BM,
                  const _Float16* __restrict__ Uh,
                  const float* __restrict__ Alog,
                  float* __restrict__ HEND, float* __restrict__ PPROD) {
    __shared__ floatx4 sdt4[CHUNK * 4];
    __shared__ floatx4 sdb4[CHUNK * 4];
    const int tid = threadIdx.x;
    const int chunk = blockIdx.x;
    const int dg = blockIdx.y;
    const int b  = blockIdx.z;
    const int d  = dg*256 + tid;
    const int l0 = chunk * CHUNK;
    if (tid < CHUNK * 4) {
        const floatx4 dtv = ((const floatx4*)(DT + (size_t)(b*SEQLEN + l0)*16))[tid];
        const floatx4 bmv = ((const floatx4*)(BM + (size_t)(b*SEQLEN + l0)*16))[tid];
        sdt4[tid] = dtv;
        sdb4[tid] = dtv * bmv;
    }
    __syncthreads();
    floatx4 A4[4];
    #pragma unroll
    for (int qq = 0; qq < 4; qq++) {
        const floatx4 av = ((const floatx4*)(Alog + (size_t)d*16))[qq];
        A4[qq].x = -__expf(av.x); A4[qq].y = -__expf(av.y);
        A4[qq].z = -__expf(av.z); A4[qq].w = -__expf(av.w);
    }
    floatx4 h4[4], P4[4];
    #pragma unroll
    for (int qq = 0; qq < 4; qq++) {
        h4[qq] = (floatx4){0.f, 0.f, 0.f, 0.f};
        P4[qq] = (floatx4){1.f, 1.f, 1.f, 1.f};
    }
    const _Float16* uhp = Uh + ((size_t)(b*SEQLEN + l0))*DINNER + d;
    #pragma unroll 4
    for (int l = 0; l < CHUNK; l++) {
        const float u = (float)uhp[(size_t)l*DINNER];
        #pragma unroll
        for (int qq = 0; qq < 4; qq++) {
            const floatx4 dtv = sdt4[l*4 + qq];
            const floatx4 dbv = sdb4[l*4 + qq];
            floatx4 dA;
            dA.x = __expf(dtv.x * A4[qq].x);
            dA.y = __expf(dtv.y * A4[qq].y);
            dA.z = __expf(dtv.z * A4[qq].z);
            dA.w = __expf(dtv.w * A4[qq].w);
            h4[qq] = dA * h4[qq] + dbv * u;
            P4[qq] *= dA;
        }
    }
    floatx4* he = (floatx4*)(HEND  + ((size_t)(b*NCHUNK + chunk)*DINNER + d)*16);
    floatx4* pp = (floatx4*)(PPROD + ((size_t)(b*NCHUNK + chunk)*DINNER + d)*16);
    #pragma unroll
    for (int qq = 0; qq < 4; qq++) {
        he[qq] = h4[qq];
        pp[qq] = P4[qq];
    }
}

// ---------------------------------------------------------------------------
// K3b: sequential chain over 128 chunks. Thread per (b,d,s) = 32768.
// ---------------------------------------------------------------------------
__global__ __launch_bounds__(256)
void scan_phase_b(const float* __restrict__ HEND, const float* __restrict__ PPROD,
                  float* __restrict__ H0) {
    const int tid = threadIdx.x;
    const int s  = tid & 15;
    const int dl = tid >> 4;
    const int blk = blockIdx.x;
    const int b  = blk >> 5;
    const int dg = blk & 31;
    const int d  = dg*16 + dl;
    float h = 0.f;
    for (int c0 = 0; c0 < NCHUNK; c0 += 8) {
        float Pv[8], Hv[8];
        #pragma unroll
        for (int j = 0; j < 8; j++) {
            const size_t idx = ((size_t)(b*NCHUNK + c0 + j)*DINNER + d)*16 + s;
            Pv[j] = PPROD[idx];
            Hv[j] = HEND [idx];
        }
        #pragma unroll
        for (int j = 0; j < 8; j++) {
            H0[((size_t)(b*NCHUNK + c0 + j)*DINNER + d)*16 + s] = h;
            h = Pv[j]*h + Hv[j];
        }
    }
}

// ---------------------------------------------------------------------------
// K3c: rerun chunks from true initial state (CHUNK=32, 1024 blocks).
// floatx4 states, b128 LDS reads; emit Y2 fp16 fused with skip+gate.
// ---------------------------------------------------------------------------
__global__ __launch_bounds__(256)
void scan_phase_c(const float* __restrict__ DT, const float* __restrict__ BM,
                  const float* __restrict__ CM,
                  const _Float16* __restrict__ Uh, const _Float16* __restrict__ Gh,
                  const float* __restrict__ Alog,
                  const float* __restrict__ Dvec, const float* __restrict__ H0,
                  _Float16* __restrict__ Y2) {
    __shared__ floatx4 sdt4[CHUNK * 4];
    __shared__ floatx4 sdb4[CHUNK * 4];
    __shared__ floatx4 sc4 [CHUNK * 4];
    const int tid = threadIdx.x;
    const int chunk = blockIdx.x;
    const int dg = blockIdx.y;
    const int b  = blockIdx.z;
    const int d  = dg*256 + tid;
    const int l0 = chunk * CHUNK;
    if (tid < CHUNK * 4) {
        const floatx4 dtv = ((const floatx4*)(DT + (size_t)(b*SEQLEN + l0)*16))[tid];
        const floatx4 bmv = ((const floatx4*)(BM + (size_t)(b*SEQLEN + l0)*16))[tid];
        sdt4[tid] = dtv;
        sdb4[tid] = dtv * bmv;
    } else {
        const int t2 = tid - CHUNK * 4;
        sc4[t2] = ((const floatx4*)(CM + (size_t)(b*SEQLEN + l0)*16))[t2];
    }
    __syncthreads();
    floatx4 A4[4];
    #pragma unroll
    for (int qq = 0; qq < 4; qq++) {
        const floatx4 av = ((const floatx4*)(Alog + (size_t)d*16))[qq];
        A4[qq].x = -__expf(av.x); A4[qq].y = -__expf(av.y);
        A4[qq].z = -__expf(av.z); A4[qq].w = -__expf(av.w);
    }
    floatx4 h4[4];
    {
        const floatx4* h0 = (const floatx4*)(H0 +
            ((size_t)(b*NCHUNK + chunk)*DINNER + d)*16);
        #pragma unroll
        for (int qq = 0; qq < 4; qq++) h4[qq] = h0[qq];
    }
    const float Dd = Dvec[d];
    const size_t base = ((size_t)(b*SEQLEN + l0))*DINNER + d;
    const _Float16* uhp = Uh + base;
    const _Float16* ghp = Gh + base;
    _Float16* yp = Y2 + base;
    #pragma unroll 4
    for (int l = 0; l < CHUNK; l++) {
        const float u = (float)uhp[(size_t)l*DINNER];
        const float g = (float)ghp[(size_t)l*DINNER];
        floatx4 y4 = {0.f, 0.f, 0.f, 0.f};
        #pragma unroll
        for (int qq = 0; qq < 4; qq++) {
            const floatx4 dtv = sdt4[l*4 + qq];
            const floatx4 dbv = sdb4[l*4 + qq];
            const floatx4 cv  = sc4 [l*4 + qq];
            floatx4 dA;
            dA.x = __expf(dtv.x * A4[qq].x);
            dA.y = __expf(dtv.y * A4[qq].y);
            dA.z = __expf(dtv.z * A4[qq].z);
            dA.w = __expf(dtv.w * A4[qq].w);
            h4[qq] = dA * h4[qq] + dbv * u;
            y4 += h4[qq] * cv;
        }
        const float y = y4.x + y4.y + y4.z + y4.w;
        yp[(size_t)l*DINNER] = (_Float16)((y + u*Dd) * g);
    }
}

// ---------------------------------------------------------------------------
extern "C" void kernel_launch(void* const* d_in, const int* in_sizes, int n_in,
                              void* d_out, int out_size, void* d_ws, size_t ws_size,
                              hipStream_t stream) {
    const float* x        = (const float*)d_in[0];
    const float* x_proj   = (const float*)d_in[1];
    const float* dt_proj  = (const float*)d_in[2];
    const float* A_log    = (const float*)d_in[3];
    const float* B_proj   = (const float*)d_in[4];
    const float* C_proj   = (const float*)d_in[5];
    const float* Dvec     = (const float*)d_in[6];
    const float* out_proj = (const float*)d_in[7];
    const float* dt_bias  = (const float*)d_in[8];
    float* out = (float*)d_out;

    float* ws = (float*)d_ws;
    float* DT   = ws;                                    // 16384*16
    float* BM   = DT   + (size_t)M_ROWS*DSTATE;
    float* CM   = BM   + (size_t)M_ROWS*DSTATE;
    float* HEND = CM   + (size_t)M_ROWS*DSTATE;          // [b][chunk][d][s]
    float* PPRO = HEND + (size_t)BATCH*NCHUNK*DINNER*DSTATE;
    float* H0   = PPRO + (size_t)BATCH*NCHUNK*DINNER*DSTATE;
    _Float16* Y2   = (_Float16*)(H0 + (size_t)BATCH*NCHUNK*DINNER*DSTATE);
    _Float16* W1h  = Y2   + (size_t)M_ROWS*DINNER;
    _Float16* W4h  = W1h  + (size_t)NDIM*1024;
    _Float16* Wphi = W4h  + (size_t)DINNER*NDIM;         // 32768 each
    _Float16* Wplo = Wphi + (size_t)32768;
    _Float16* Uh   = Wplo + (size_t)32768;               // 16384*512
    _Float16* Gh   = Uh   + (size_t)M_ROWS*DINNER;

    prep_all<<<dim3(1664), 256, 0, stream>>>(x_proj, out_proj, dt_proj,
                                             B_proj, C_proj,
                                             W1h, W4h, Wphi, Wplo);
    mfma_gemm1<<<dim3(1024), 256, 0, stream>>>(x, W1h, Uh, Gh);
    proj_mfma<<<dim3(M_ROWS/64), 256, 0, stream>>>(Uh, Wphi, Wplo,
                                                   dt_bias, DT, BM, CM);
    scan_phase_a<<<dim3(NCHUNK, DINNER/256, BATCH), 256, 0, stream>>>(
        DT, BM, Uh, A_log, HEND, PPRO);
    scan_phase_b<<<dim3(128), 256, 0, stream>>>(HEND, PPRO, H0);
    scan_phase_c<<<dim3(NCHUNK, DINNER/256, BATCH), 256, 0, stream>>>(
        DT, BM, CM, Uh, Gh, A_log, Dvec, H0, Y2);
    mfma_gemm4<<<dim3(512), 256, 0, stream>>>(Y2, W4h, out);
}

// Round 15
// 218.342 us; speedup vs baseline: 1.0582x; 1.0582x over previous
//
#include <hip/hip_runtime.h>
#include <math.h>

#define BATCH   4
#define SEQLEN  4096
#define NDIM    256
#define DINNER  512
#define DSTATE  16
#define M_ROWS  (BATCH*SEQLEN)   // 16384
#define CHUNK   32
#define NCHUNK  (SEQLEN/CHUNK)   // 128

typedef _Float16 half8 __attribute__((ext_vector_type(8)));
typedef _Float16 half4 __attribute__((ext_vector_type(4)));
typedef float floatx4 __attribute__((ext_vector_type(4)));

// ---------------------------------------------------------------------------
// prep_all: x conversion + weight packing, one dispatch.
// blocks [0,4096): x -> Xh fp16 row-major
// blocks [4096,5120): x_proj -> W1h B-frag order
// blocks [5120,5632): out_proj -> W4h B-frag order
// blocks [5632,5760): [Wdt|Wb|Wc|0] -> Wphi/Wplo B-frag order (hi/lo)
// ---------------------------------------------------------------------------
__global__ __launch_bounds__(256)
void prep_all(const float* __restrict__ X, const float* __restrict__ Wx,
              const float* __restrict__ Wo, const float* __restrict__ Wdt,
              const float* __restrict__ Wb, const float* __restrict__ Wc,
              _Float16* __restrict__ Xh, _Float16* __restrict__ W1h,
              _Float16* __restrict__ W4h, _Float16* __restrict__ Wphi,
              _Float16* __restrict__ Wplo) {
    const int bid = blockIdx.x;
    const int tid = threadIdx.x;
    if (bid < 4096) {
        const size_t t = (size_t)bid * 256 + tid;
        const float4 v = ((const float4*)X)[t];
        half4 h;
        h.x = (_Float16)v.x; h.y = (_Float16)v.y;
        h.z = (_Float16)v.z; h.w = (_Float16)v.w;
        ((half4*)Xh)[t] = h;
    } else if (bid < 5120) {
        const int t = (bid - 4096) * 256 + tid;      // x_proj: N=1024
        const int j  = t & 7;
        const int n  = (t >> 3) & 1023;
        const int q  = (t >> 13) & 3;
        const int kb = t >> 15;
        const int k  = kb * 32 + q * 8 + j;
        W1h[t] = (_Float16)Wx[(size_t)k * 1024 + n];
    } else if (bid < 5632) {
        const int t = (bid - 5120) * 256 + tid;      // out_proj: N=256
        const int j  = t & 7;
        const int n  = (t >> 3) & 255;
        const int q  = (t >> 11) & 3;
        const int kb = t >> 13;
        const int k  = kb * 32 + q * 8 + j;
        W4h[t] = (_Float16)Wo[(size_t)k * 256 + n];
    } else {
        const int t = (bid - 5632) * 256 + tid;      // proj weights, N=64
        const int n  = (t >> 3) & 63;
        const int q  = (t >> 9) & 3;
        const int kb = t >> 11;
        const int k  = kb * 32 + q * 8 + (t & 7);
        float v;
        if      (n < 16) v = Wdt[(size_t)k * 16 + n];
        else if (n < 32) v = Wb [(size_t)k * 16 + (n - 16)];
        else if (n < 48) v = Wc [(size_t)k * 16 + (n - 32)];
        else             v = 0.f;
        const _Float16 hi = (_Float16)v;
        Wphi[t] = hi;
        Wplo[t] = (_Float16)(v - (float)hi);
    }
}

// ---------------------------------------------------------------------------
// K1: fp16 MFMA GEMM, NO LDS, XCD-swizzled, REGISTER PING-PONG PREFETCH:
// kb+1's A/B frags load into the alternate register set while kb's MFMAs
// run — hides L2 latency without barriers (the vmcnt serialization was the
// ~45us -> floor gap). silu -> fp16 U / G.
// ---------------------------------------------------------------------------
__global__ __launch_bounds__(256)
void mfma_gemm1(const _Float16* __restrict__ Ah, const _Float16* __restrict__ Wh,
                _Float16* __restrict__ O1, _Float16* __restrict__ O2) {
    const int KT = 256, NT = 1024;
    const int bid = blockIdx.x;
    const int by = bid & 127;
    const int bx = bid >> 7;
    const int tid = threadIdx.x;
    const int lane = tid & 63;
    const int w  = tid >> 6;
    const int wm = w >> 1, wn = w & 1;
    const int n0 = bx * 128;
    const int m0 = by * 128;
    const int l15 = lane & 15, q = lane >> 4;

    floatx4 acc[4][4];
    const floatx4 zero = {0.f, 0.f, 0.f, 0.f};
    #pragma unroll
    for (int i = 0; i < 4; i++)
        #pragma unroll
        for (int j = 0; j < 4; j++) acc[i][j] = zero;

    const _Float16* aBase = Ah + (size_t)(m0 + wm * 64 + l15) * KT + q * 8;
    const _Float16* wBase = Wh + ((size_t)q * NT + n0 + wn * 64 + l15) * 8;
    // A frag (kb, mt): aBase + mt*16*KT + kb*32
    // B frag (kb, nt): wBase + kb*NT*32 + nt*128

    half8 a0[4], b0[4], a1[4], b1[4];
    #pragma unroll
    for (int mt = 0; mt < 4; mt++)
        a0[mt] = *(const half8*)(aBase + (size_t)(mt * 16) * KT);
    #pragma unroll
    for (int nt = 0; nt < 4; nt++)
        b0[nt] = *(const half8*)(wBase + nt * 128);

    #pragma unroll
    for (int kb = 0; kb < 8; kb += 2) {
        // prefetch kb+1 into alt set
        #pragma unroll
        for (int mt = 0; mt < 4; mt++)
            a1[mt] = *(const half8*)(aBase + (size_t)(mt * 16) * KT + (kb + 1) * 32);
        #pragma unroll
        for (int nt = 0; nt < 4; nt++)
            b1[nt] = *(const half8*)(wBase + (size_t)(kb + 1) * NT * 32 + nt * 128);
        #pragma unroll
        for (int mt = 0; mt < 4; mt++)
            #pragma unroll
            for (int nt = 0; nt < 4; nt++)
                acc[mt][nt] = __builtin_amdgcn_mfma_f32_16x16x32_f16(
                    a0[mt], b0[nt], acc[mt][nt], 0, 0, 0);
        if (kb + 2 < 8) {   // prefetch kb+2 into primary set (compile-time)
            #pragma unroll
            for (int mt = 0; mt < 4; mt++)
                a0[mt] = *(const half8*)(aBase + (size_t)(mt * 16) * KT + (kb + 2) * 32);
            #pragma unroll
            for (int nt = 0; nt < 4; nt++)
                b0[nt] = *(const half8*)(wBase + (size_t)(kb + 2) * NT * 32 + nt * 128);
        }
        #pragma unroll
        for (int mt = 0; mt < 4; mt++)
            #pragma unroll
            for (int nt = 0; nt < 4; nt++)
                acc[mt][nt] = __builtin_amdgcn_mfma_f32_16x16x32_f16(
                    a1[mt], b1[nt], acc[mt][nt], 0, 0, 0);
    }
    // epilogue: D col=lane&15, row=quad*4+reg  [verified m89/m91; dtype-indep]
    #pragma unroll
    for (int mt = 0; mt < 4; mt++) {
        #pragma unroll
        for (int nt = 0; nt < 4; nt++) {
            const int col = n0 + wn * 64 + nt * 16 + l15;
            #pragma unroll
            for (int r = 0; r < 4; r++) {
                const int row = m0 + wm * 64 + mt * 16 + q * 4 + r;
                float v = acc[mt][nt][r];
                v = v / (1.f + __expf(-v));
                if (col < DINNER) O1[(size_t)row * DINNER + col] = (_Float16)v;
                else              O2[(size_t)row * DINNER + col - DINNER] = (_Float16)v;
            }
        }
    }
}

// ---------------------------------------------------------------------------
// K4: fp16 MFMA GEMM, NO LDS, XCD-swizzled, register ping-pong prefetch.
// Out fp32.
// ---------------------------------------------------------------------------
__global__ __launch_bounds__(256)
void mfma_gemm4(const _Float16* __restrict__ Ah, const _Float16* __restrict__ Wh,
                float* __restrict__ Out) {
    const int KT = 512, NT = 256;
    const int bid = blockIdx.x;
    const int by = bid & 127;
    const int bx = bid >> 7;
    const int tid = threadIdx.x;
    const int lane = tid & 63;
    const int w  = tid >> 6;
    const int wm = w >> 1, wn = w & 1;
    const int n0 = bx * 64;
    const int m0 = by * 128;
    const int l15 = lane & 15, q = lane >> 4;

    floatx4 acc[4][2];
    const floatx4 zero = {0.f, 0.f, 0.f, 0.f};
    #pragma unroll
    for (int i = 0; i < 4; i++)
        #pragma unroll
        for (int j = 0; j < 2; j++) acc[i][j] = zero;

    const _Float16* aBase = Ah + (size_t)(m0 + wm * 64 + l15) * KT + q * 8;
    const _Float16* wBase = Wh + ((size_t)q * NT + n0 + wn * 32 + l15) * 8;
    // A frag (kb, mt): aBase + mt*16*KT + kb*32
    // B frag (kb, nt): wBase + kb*NT*32 + nt*128

    half8 a0[4], b0[2], a1[4], b1[2];
    #pragma unroll
    for (int mt = 0; mt < 4; mt++)
        a0[mt] = *(const half8*)(aBase + (size_t)(mt * 16) * KT);
    #pragma unroll
    for (int nt = 0; nt < 2; nt++)
        b0[nt] = *(const half8*)(wBase + nt * 128);

    #pragma unroll
    for (int kb = 0; kb < 16; kb += 2) {
        #pragma unroll
        for (int mt = 0; mt < 4; mt++)
            a1[mt] = *(const half8*)(aBase + (size_t)(mt * 16) * KT + (kb + 1) * 32);
        #pragma unroll
        for (int nt = 0; nt < 2; nt++)
            b1[nt] = *(const half8*)(wBase + (size_t)(kb + 1) * NT * 32 + nt * 128);
        #pragma unroll
        for (int mt = 0; mt < 4; mt++)
            #pragma unroll
            for (int nt = 0; nt < 2; nt++)
                acc[mt][nt] = __builtin_amdgcn_mfma_f32_16x16x32_f16(
                    a0[mt], b0[nt], acc[mt][nt], 0, 0, 0);
        if (kb + 2 < 16) {
            #pragma unroll
            for (int mt = 0; mt < 4; mt++)
                a0[mt] = *(const half8*)(aBase + (size_t)(mt * 16) * KT + (kb + 2) * 32);
            #pragma unroll
            for (int nt = 0; nt < 2; nt++)
                b0[nt] = *(const half8*)(wBase + (size_t)(kb + 2) * NT * 32 + nt * 128);
        }
        #pragma unroll
        for (int mt = 0; mt < 4; mt++)
            #pragma unroll
            for (int nt = 0; nt < 2; nt++)
                acc[mt][nt] = __builtin_amdgcn_mfma_f32_16x16x32_f16(
                    a1[mt], b1[nt], acc[mt][nt], 0, 0, 0);
    }
    #pragma unroll
    for (int mt = 0; mt < 4; mt++) {
        #pragma unroll
        for (int nt = 0; nt < 2; nt++) {
            const int col = n0 + wn * 32 + nt * 16 + l15;
            #pragma unroll
            for (int r = 0; r < 4; r++) {
                const int row = m0 + wm * 64 + mt * 16 + q * 4 + r;
                Out[(size_t)row * NT + col] = acc[mt][nt][r];
            }
        }
    }
}

// ---------------------------------------------------------------------------
// proj_mfma (2-product, NO LDS): U fp16 @ Wp (512x64 hi/lo; 48 real cols) ->
// DT (softplus+bias) / BM / CM. 256 blocks x 64 rows.
// ---------------------------------------------------------------------------
__global__ __launch_bounds__(256)
void proj_mfma(const _Float16* __restrict__ Uh,
               const _Float16* __restrict__ Whi, const _Float16* __restrict__ Wlo,
               const float* __restrict__ bias,
               float* __restrict__ DT, float* __restrict__ BM,
               float* __restrict__ CM) {
    const int tid = threadIdx.x;
    const int lane = tid & 63;
    const int w  = tid >> 6;
    const int wm = w >> 1, wn = w & 1;
    const int m0 = blockIdx.x * 64;
    const int l15 = lane & 15, q = lane >> 4;

    floatx4 acc[2][2];
    const floatx4 zero = {0.f, 0.f, 0.f, 0.f};
    #pragma unroll
    for (int i = 0; i < 2; i++)
        #pragma unroll
        for (int j = 0; j < 2; j++) acc[i][j] = zero;

    const _Float16* aBase = Uh + (size_t)(m0 + wm * 32 + l15) * DINNER + q * 8;

    for (int kb = 0; kb < DINNER / 32; kb++) {
        half8 bh[2], bl[2], a[2];
        #pragma unroll
        for (int mt = 0; mt < 2; mt++)
            a[mt] = *(const half8*)(aBase + (size_t)(mt * 16) * DINNER + kb * 32);
        #pragma unroll
        for (int nt = 0; nt < 2; nt++) {
            const size_t off =
                ((size_t)((kb * 4 + q) * 64) + wn * 32 + nt * 16 + l15) * 8;
            bh[nt] = *(const half8*)(Whi + off);
            bl[nt] = *(const half8*)(Wlo + off);
        }
        #pragma unroll
        for (int mt = 0; mt < 2; mt++)
            #pragma unroll
            for (int nt = 0; nt < 2; nt++) {
                acc[mt][nt] = __builtin_amdgcn_mfma_f32_16x16x32_f16(
                    a[mt], bh[nt], acc[mt][nt], 0, 0, 0);
                acc[mt][nt] = __builtin_amdgcn_mfma_f32_16x16x32_f16(
                    a[mt], bl[nt], acc[mt][nt], 0, 0, 0);
            }
    }
    #pragma unroll
    for (int mt = 0; mt < 2; mt++) {
        #pragma unroll
        for (int nt = 0; nt < 2; nt++) {
            const int col = wn * 32 + nt * 16 + l15;
            #pragma unroll
            for (int r = 0; r < 4; r++) {
                const int row = m0 + wm * 32 + mt * 16 + q * 4 + r;
                float v = acc[mt][nt][r];
                if (col < 16) {
                    float dv = v + bias[col];
                    dv = (dv > 20.f) ? dv : log1pf(__expf(dv));
                    DT[(size_t)row * 16 + col] = dv;
                } else if (col < 32) {
                    BM[(size_t)row * 16 + (col - 16)] = v;
                } else if (col < 48) {
                    CM[(size_t)row * 16 + (col - 32)] = v;
                }
            }
        }
    }
}

// ---------------------------------------------------------------------------
// K3a: chunked scan phase A (CHUNK=32, 1024 blocks). One thread per d;
// states in floatx4[4]; LDS read as b128. [3-dispatch scan is the proven
// form: cooperative grid.sync under graph capture failed — R13.]
// ---------------------------------------------------------------------------
__global__ __launch_bounds__(256)
void scan_phase_a(const float* __restrict__ DT, const float* __restrict__ BM,
                  const _Float16* __restrict__ Uh,
                  const float* __restrict__ Alog,
                  float* __restrict__ HEND, float* __restrict__ PPROD) {
    __shared__ floatx4 sdt4[CHUNK * 4];
    __shared__ floatx4 sdb4[CHUNK * 4];
    const int tid = threadIdx.x;
    const int chunk = blockIdx.x;
    const int dg = blockIdx.y;
    const int b  = blockIdx.z;
    const int d  = dg*256 + tid;
    const int l0 = chunk * CHUNK;
    if (tid < CHUNK * 4) {
        const floatx4 dtv = ((const floatx4*)(DT + (size_t)(b*SEQLEN + l0)*16))[tid];
        const floatx4 bmv = ((const floatx4*)(BM + (size_t)(b*SEQLEN + l0)*16))[tid];
        sdt4[tid] = dtv;
        sdb4[tid] = dtv * bmv;
    }
    __syncthreads();
    floatx4 A4[4];
    #pragma unroll
    for (int qq = 0; qq < 4; qq++) {
        const floatx4 av = ((const floatx4*)(Alog + (size_t)d*16))[qq];
        A4[qq].x = -__expf(av.x); A4[qq].y = -__expf(av.y);
        A4[qq].z = -__expf(av.z); A4[qq].w = -__expf(av.w);
    }
    floatx4 h4[4], P4[4];
    #pragma unroll
    for (int qq = 0; qq < 4; qq++) {
        h4[qq] = (floatx4){0.f, 0.f, 0.f, 0.f};
        P4[qq] = (floatx4){1.f, 1.f, 1.f, 1.f};
    }
    const _Float16* uhp = Uh + ((size_t)(b*SEQLEN + l0))*DINNER + d;
    #pragma unroll 4
    for (int l = 0; l < CHUNK; l++) {
        const float u = (float)uhp[(size_t)l*DINNER];
        #pragma unroll
        for (int qq = 0; qq < 4; qq++) {
            const floatx4 dtv = sdt4[l*4 + qq];
            const floatx4 dbv = sdb4[l*4 + qq];
            floatx4 dA;
            dA.x = __expf(dtv.x * A4[qq].x);
            dA.y = __expf(dtv.y * A4[qq].y);
            dA.z = __expf(dtv.z * A4[qq].z);
            dA.w = __expf(dtv.w * A4[qq].w);
            h4[qq] = dA * h4[qq] + dbv * u;
            P4[qq] *= dA;
        }
    }
    floatx4* he = (floatx4*)(HEND  + ((size_t)(b*NCHUNK + chunk)*DINNER + d)*16);
    floatx4* pp = (floatx4*)(PPROD + ((size_t)(b*NCHUNK + chunk)*DINNER + d)*16);
    #pragma unroll
    for (int qq = 0; qq < 4; qq++) {
        he[qq] = h4[qq];
        pp[qq] = P4[qq];
    }
}

// ---------------------------------------------------------------------------
// K3b: sequential chain over 128 chunks. Thread per (b,d,s) = 32768.
// ---------------------------------------------------------------------------
__global__ __launch_bounds__(256)
void scan_phase_b(const float* __restrict__ HEND, const float* __restrict__ PPROD,
                  float* __restrict__ H0) {
    const int tid = threadIdx.x;
    const int s  = tid & 15;
    const int dl = tid >> 4;
    const int blk = blockIdx.x;
    const int b  = blk >> 5;
    const int dg = blk & 31;
    const int d  = dg*16 + dl;
    float h = 0.f;
    for (int c0 = 0; c0 < NCHUNK; c0 += 8) {
        float Pv[8], Hv[8];
        #pragma unroll
        for (int j = 0; j < 8; j++) {
            const size_t idx = ((size_t)(b*NCHUNK + c0 + j)*DINNER + d)*16 + s;
            Pv[j] = PPROD[idx];
            Hv[j] = HEND [idx];
        }
        #pragma unroll
        for (int j = 0; j < 8; j++) {
            H0[((size_t)(b*NCHUNK + c0 + j)*DINNER + d)*16 + s] = h;
            h = Pv[j]*h + Hv[j];
        }
    }
}

// ---------------------------------------------------------------------------
// K3c: rerun chunks from true initial state (CHUNK=32, 1024 blocks).
// floatx4 states, b128 LDS reads; emit Y2 fp16 fused with skip+gate.
// ---------------------------------------------------------------------------
__global__ __launch_bounds__(256)
void scan_phase_c(const float* __restrict__ DT, const float* __restrict__ BM,
                  const float* __restrict__ CM,
                  const _Float16* __restrict__ Uh, const _Float16* __restrict__ Gh,
                  const float* __restrict__ Alog,
                  const float* __restrict__ Dvec, const float* __restrict__ H0,
                  _Float16* __restrict__ Y2) {
    __shared__ floatx4 sdt4[CHUNK * 4];
    __shared__ floatx4 sdb4[CHUNK * 4];
    __shared__ floatx4 sc4 [CHUNK * 4];
    const int tid = threadIdx.x;
    const int chunk = blockIdx.x;
    const int dg = blockIdx.y;
    const int b  = blockIdx.z;
    const int d  = dg*256 + tid;
    const int l0 = chunk * CHUNK;
    if (tid < CHUNK * 4) {
        const floatx4 dtv = ((const floatx4*)(DT + (size_t)(b*SEQLEN + l0)*16))[tid];
        const floatx4 bmv = ((const floatx4*)(BM + (size_t)(b*SEQLEN + l0)*16))[tid];
        sdt4[tid] = dtv;
        sdb4[tid] = dtv * bmv;
    } else {
        const int t2 = tid - CHUNK * 4;
        sc4[t2] = ((const floatx4*)(CM + (size_t)(b*SEQLEN + l0)*16))[t2];
    }
    __syncthreads();
    floatx4 A4[4];
    #pragma unroll
    for (int qq = 0; qq < 4; qq++) {
        const floatx4 av = ((const floatx4*)(Alog + (size_t)d*16))[qq];
        A4[qq].x = -__expf(av.x); A4[qq].y = -__expf(av.y);
        A4[qq].z = -__expf(av.z); A4[qq].w = -__expf(av.w);
    }
    floatx4 h4[4];
    {
        const floatx4* h0 = (const floatx4*)(H0 +
            ((size_t)(b*NCHUNK + chunk)*DINNER + d)*16);
        #pragma unroll
        for (int qq = 0; qq < 4; qq++) h4[qq] = h0[qq];
    }
    const float Dd = Dvec[d];
    const size_t base = ((size_t)(b*SEQLEN + l0))*DINNER + d;
    const _Float16* uhp = Uh + base;
    const _Float16* ghp = Gh + base;
    _Float16* yp = Y2 + base;
    #pragma unroll 4
    for (int l = 0; l < CHUNK; l++) {
        const float u = (float)uhp[(size_t)l*DINNER];
        const float g = (float)ghp[(size_t)l*DINNER];
        floatx4 y4 = {0.f, 0.f, 0.f, 0.f};
        #pragma unroll
        for (int qq = 0; qq < 4; qq++) {
            const floatx4 dtv = sdt4[l*4 + qq];
            const floatx4 dbv = sdb4[l*4 + qq];
            const floatx4 cv  = sc4 [l*4 + qq];
            floatx4 dA;
            dA.x = __expf(dtv.x * A4[qq].x);
            dA.y = __expf(dtv.y * A4[qq].y);
            dA.z = __expf(dtv.z * A4[qq].z);
            dA.w = __expf(dtv.w * A4[qq].w);
            h4[qq] = dA * h4[qq] + dbv * u;
            y4 += h4[qq] * cv;
        }
        const float y = y4.x + y4.y + y4.z + y4.w;
        yp[(size_t)l*DINNER] = (_Float16)((y + u*Dd) * g);
    }
}

// ---------------------------------------------------------------------------
extern "C" void kernel_launch(void* const* d_in, const int* in_sizes, int n_in,
                              void* d_out, int out_size, void* d_ws, size_t ws_size,
                              hipStream_t stream) {
    const float* x        = (const float*)d_in[0];
    const float* x_proj   = (const float*)d_in[1];
    const float* dt_proj  = (const float*)d_in[2];
    const float* A_log    = (const float*)d_in[3];
    const float* B_proj   = (const float*)d_in[4];
    const float* C_proj   = (const float*)d_in[5];
    const float* Dvec     = (const float*)d_in[6];
    const float* out_proj = (const float*)d_in[7];
    const float* dt_bias  = (const float*)d_in[8];
    float* out = (float*)d_out;

    float* ws = (float*)d_ws;
    float* DT   = ws;                                    // 16384*16
    float* BM   = DT   + (size_t)M_ROWS*DSTATE;
    float* CM   = BM   + (size_t)M_ROWS*DSTATE;
    float* HEND = CM   + (size_t)M_ROWS*DSTATE;          // [b][chunk][d][s]
    float* PPRO = HEND + (size_t)BATCH*NCHUNK*DINNER*DSTATE;
    float* H0   = PPRO + (size_t)BATCH*NCHUNK*DINNER*DSTATE;
    _Float16* Y2   = (_Float16*)(H0 + (size_t)BATCH*NCHUNK*DINNER*DSTATE);
    _Float16* W1h  = Y2   + (size_t)M_ROWS*DINNER;
    _Float16* W4h  = W1h  + (size_t)NDIM*1024;
    _Float16* Wphi = W4h  + (size_t)DINNER*NDIM;         // 32768 each
    _Float16* Wplo = Wphi + (size_t)32768;
    _Float16* Uh   = Wplo + (size_t)32768;               // 16384*512
    _Float16* Gh   = Uh   + (size_t)M_ROWS*DINNER;
    _Float16* Xh   = Gh   + (size_t)M_ROWS*DINNER;       // 16384*256

    prep_all<<<dim3(5760), 256, 0, stream>>>(x, x_proj, out_proj, dt_proj,
                                             B_proj, C_proj,
                                             Xh, W1h, W4h, Wphi, Wplo);
    mfma_gemm1<<<dim3(1024), 256, 0, stream>>>(Xh, W1h, Uh, Gh);
    proj_mfma<<<dim3(M_ROWS/64), 256, 0, stream>>>(Uh, Wphi, Wplo,
                                                   dt_bias, DT, BM, CM);
    scan_phase_a<<<dim3(NCHUNK, DINNER/256, BATCH), 256, 0, stream>>>(
        DT, BM, Uh, A_log, HEND, PPRO);
    scan_phase_b<<<dim3(128), 256, 0, stream>>>(HEND, PPRO, H0);
    scan_phase_c<<<dim3(NCHUNK, DINNER/256, BATCH), 256, 0, stream>>>(
        DT, BM, CM, Uh, Gh, A_log, Dvec, H0, Y2);
    mfma_gemm4<<<dim3(512), 256, 0, stream>>>(Y2, W4h, out);
}